// Round 4
// baseline (352.614 us; speedup 1.0000x reference)
//
#include <hip/hip_runtime.h>
#include <stdint.h>

#define NN 50000
#define NE 800000
#define NRP 50048      // padded rows (multiple of 64)
#define GG 782         // gemm grid: (NN + 63) / 64
#define NB 196         // hi buckets: ceil(NN / 256)
#define TT 2048        // edges per scatter block
#define SB 391         // scatter blocks: ceil(NE / TT)
#define SLAB 8192      // packA slab stride per bucket
#define SLABE (NRP * 32)  // ushort elements per 32-feature slab
#define SLABU (NRP * 16)  // uint32 elements per 32-feature slab

typedef __attribute__((ext_vector_type(8))) short bfx8;   // 8 bf16 (4 VGPRs)
typedef __attribute__((ext_vector_type(4))) float f32x4;  // MFMA acc

// ---- bf16 helpers (RNE) ----
__device__ inline unsigned short f2bf(float f) {
    union { float f; uint32_t u; } x; x.f = f;
    uint32_t u = x.u;
    return (unsigned short)((u + 0x7fffu + ((u >> 16) & 1u)) >> 16);
}
__device__ inline uint32_t pack2bf(float lo, float hi) {
    return (uint32_t)f2bf(lo) | ((uint32_t)f2bf(hi) << 16);
}
__device__ inline float bf2f(unsigned short h) {
    union { uint32_t u; float f; } c; c.u = ((uint32_t)h) << 16;
    return c.f;
}
__device__ inline float2 bfp2f2(uint32_t v) {
    union { uint32_t u; float f; } a, b;
    a.u = (v & 0xffffu) << 16;
    b.u = v & 0xffff0000u;
    return make_float2(a.f, b.f);
}
__device__ inline bfx8 ld8(const unsigned short* p) {
    union { uint4 u; bfx8 v; } c;
    c.u = *(const uint4*)p;
    return c.v;
}
__device__ inline bfx8 cvt8(float4 u, float4 v) {
    union { unsigned short s[8]; bfx8 r; } c;
    c.s[0] = f2bf(u.x); c.s[1] = f2bf(u.y); c.s[2] = f2bf(u.z); c.s[3] = f2bf(u.w);
    c.s[4] = f2bf(v.x); c.s[5] = f2bf(v.y); c.s[6] = f2bf(v.z); c.s[7] = f2bf(v.w);
    return c.r;
}

// ---------- D1: W transposes + zero bucket cursors ----------
__global__ void prep(const float* __restrict__ W1, const float* __restrict__ W2,
                     const float* __restrict__ W3,
                     unsigned short* __restrict__ WT1, unsigned short* __restrict__ WT2,
                     unsigned short* __restrict__ WT3, int* __restrict__ cursor) {
    if (blockIdx.x == 152) {
        if (threadIdx.x < NB) cursor[threadIdx.x] = 0;
        return;
    }
    int w = blockIdx.x * 256 + threadIdx.x;
    if (w < 16384) {
        int nn = w >> 7, k = w & 127;
        WT1[nn * 128 + k] = f2bf(W1[k * 128 + nn]);
    } else if (w < 32768) {
        int w2 = w - 16384, nn = w2 >> 7, k = w2 & 127;
        WT2[nn * 128 + k] = f2bf(W2[k * 128 + nn]);
    } else if (w < 38912) {
        int w2 = w - 32768, nn = w2 >> 7, k = w2 & 127;  // 48x128, zero-pad
        WT3[nn * 128 + k] = (nn < 40) ? f2bf(W3[k * 40 + nn]) : (unsigned short)0;
    }
}

// ---------- D2: layer-1 GEMM (slab-major out) ∪ bucket-scatter ----------
// R4: bufG/bufA are stored as 4 feature-slabs of 32 feats (3.2MB each) so the
// edge gather in aggX becomes per-XCD L2-local. Epilogue stores slab-major.
__global__ __launch_bounds__(256) void gemm1_hist(const float* __restrict__ X,
                                                  const unsigned short* __restrict__ WT,
                                                  unsigned short* __restrict__ G, int n,
                                                  const int* __restrict__ src,
                                                  const int* __restrict__ dst,
                                                  int* __restrict__ cursor,
                                                  uint32_t* __restrict__ packA, int e) {
    __shared__ int lc[NB];
    __shared__ int gb[NB];
    if (blockIdx.x >= GG) {
        int b = blockIdx.x - GG;
        int t = threadIdx.x;
        if (t < NB) lc[t] = 0;
        __syncthreads();
        int start = b * TT;
        int end = start + TT; if (end > e) end = e;
        int hi_[8], r_[8];
        uint32_t pk_[8];
#pragma unroll
        for (int j = 0; j < 8; j++) {
            int i = start + j * 256 + t;
            if (i < end) {
                int dd = dst[i], ss = src[i];
                hi_[j] = dd >> 8;
                pk_[j] = ((uint32_t)dd << 16) | (uint32_t)ss;
                r_[j] = atomicAdd(&lc[hi_[j]], 1);  // LDS rank
            } else r_[j] = -1;
        }
        __syncthreads();
        if (t < NB) {
            int c = lc[t];
            gb[t] = c ? atomicAdd(&cursor[t], c) : 0;  // global slab reservation
        }
        __syncthreads();
#pragma unroll
        for (int j = 0; j < 8; j++) {
            if (r_[j] >= 0)
                packA[(size_t)hi_[j] * SLAB + gb[hi_[j]] + r_[j]] = pk_[j];
        }
        return;
    }
    int wave = threadIdx.x >> 6;
    int lane = threadIdx.x & 63;
    int quad = lane >> 4;
    int c = lane & 15;
    int rowbase = blockIdx.x * 64 + wave * 16;

    int arow = rowbase + c;
    if (arow >= n) arow = n - 1;
    const float* ap = X + (size_t)arow * 128 + quad * 8;
    bfx8 a[4];
#pragma unroll
    for (int kc = 0; kc < 4; kc++) {
        float4 u = *(const float4*)(ap + kc * 32);
        float4 v = *(const float4*)(ap + kc * 32 + 4);
        a[kc] = cvt8(u, v);
    }

    f32x4 acc[8];
#pragma unroll
    for (int ct = 0; ct < 8; ct++) acc[ct] = (f32x4){0.f, 0.f, 0.f, 0.f};
#pragma unroll
    for (int ct = 0; ct < 8; ct++) {
        const unsigned short* bp = WT + (size_t)(ct * 16 + c) * 128 + quad * 8;
#pragma unroll
        for (int kc = 0; kc < 4; kc++) {
            bfx8 b = ld8(bp + kc * 32);
            acc[ct] = __builtin_amdgcn_mfma_f32_16x16x32_bf16(a[kc], b, acc[ct], 0, 0, 0);
        }
    }

    int r0 = rowbase + quad * 4;
    bool odd = lane & 1;
    uint32_t* Gu = (uint32_t*)G;
#pragma unroll
    for (int ct = 0; ct < 8; ct++) {
        float x0 = acc[ct][0], x1 = acc[ct][1], x2 = acc[ct][2], x3 = acc[ct][3];
        float y0 = __shfl_xor(x0, 1, 64), y1 = __shfl_xor(x1, 1, 64);
        float y2 = __shfl_xor(x2, 1, 64), y3 = __shfl_xor(x3, 1, 64);
        int colp = ct * 16 + (c & ~1);
        size_t sbase = (size_t)(colp >> 5) * SLABU + ((colp & 31) >> 1);
        if (!odd) {
            if (r0 + 0 < n) Gu[sbase + (size_t)(r0 + 0) * 16] = pack2bf(x0, y0);
            if (r0 + 1 < n) Gu[sbase + (size_t)(r0 + 1) * 16] = pack2bf(x1, y1);
        } else {
            if (r0 + 2 < n) Gu[sbase + (size_t)(r0 + 2) * 16] = pack2bf(y2, x2);
            if (r0 + 3 < n) Gu[sbase + (size_t)(r0 + 3) * 16] = pack2bf(y3, x3);
        }
    }
}

// ---------- D3: per-bucket fine sort -> row_ptr/deg/dinv + csr_src ----------
__global__ __launch_bounds__(256) void buildB(const uint32_t* __restrict__ packA,
                                              const int* __restrict__ cursor,
                                              int* __restrict__ row_ptr, int* __restrict__ deg,
                                              float* __restrict__ dinv,
                                              unsigned short* __restrict__ csr_src, int n) {
    __shared__ int s[256];
    __shared__ int cnt[256];
    __shared__ int rp[256];
    __shared__ int basehi, bcnt;
    int hi = blockIdx.x;
    int t = threadIdx.x;
    int bc = (t < NB) ? cursor[t] : 0;
    s[t] = bc;
    __syncthreads();
#pragma unroll
    for (int off = 1; off < 256; off <<= 1) {
        int y = (t >= off) ? s[t - off] : 0;
        __syncthreads();
        s[t] += y;
        __syncthreads();
    }
    if (t == hi) { basehi = s[t] - bc; bcnt = bc; }
    cnt[t] = 0;
    __syncthreads();
    int b0 = basehi;
    int mc = bcnt;
    const uint32_t* slab = packA + (size_t)hi * SLAB;
    for (int i = t; i < mc; i += 256)
        atomicAdd(&cnt[(slab[i] >> 16) & 0xFF], 1);  // LDS
    __syncthreads();
    int v = cnt[t];
    s[t] = v;
    __syncthreads();
#pragma unroll
    for (int off = 1; off < 256; off <<= 1) {
        int y = (t >= off) ? s[t - off] : 0;
        __syncthreads();
        s[t] += y;
        __syncthreads();
    }
    rp[t] = b0 + s[t] - v;  // absolute row start for node hi*256+t
    int node = hi * 256 + t;
    if (node < n) {
        row_ptr[node] = rp[t];
        deg[node] = v;
        dinv[node] = rsqrtf(1.0f + (float)v);
    }
    cnt[t] = 0;
    __syncthreads();
    for (int i = t; i < mc; i += 256) {
        uint32_t p = slab[i];
        int lo = (p >> 16) & 0xFF;
        int r = atomicAdd(&cnt[lo], 1);  // LDS
        csr_src[rp[lo] + r] = (unsigned short)(p & 0xFFFF);
    }
}

// ---------- layer-2 GEMM: slab-major A in, slab-major (dinv-scaled) out ----------
__global__ __launch_bounds__(256) void gemm128_mfma(const unsigned short* __restrict__ A,
                                                    const unsigned short* __restrict__ WT,
                                                    const float* __restrict__ dinv,
                                                    unsigned short* __restrict__ G, int n) {
    int wave = threadIdx.x >> 6;
    int lane = threadIdx.x & 63;
    int quad = lane >> 4;
    int c = lane & 15;
    int rowbase = blockIdx.x * 64 + wave * 16;

    int arow = rowbase + c;
    if (arow >= n) arow = n - 1;
    const unsigned short* ap = A + (size_t)arow * 32 + quad * 8;  // slab-major
    bfx8 a[4];
#pragma unroll
    for (int kc = 0; kc < 4; kc++) a[kc] = ld8(ap + (size_t)kc * SLABE);

    f32x4 acc[8];
#pragma unroll
    for (int ct = 0; ct < 8; ct++) acc[ct] = (f32x4){0.f, 0.f, 0.f, 0.f};
#pragma unroll
    for (int ct = 0; ct < 8; ct++) {
        const unsigned short* bp = WT + (size_t)(ct * 16 + c) * 128 + quad * 8;
#pragma unroll
        for (int kc = 0; kc < 4; kc++) {
            bfx8 b = ld8(bp + kc * 32);
            acc[ct] = __builtin_amdgcn_mfma_f32_16x16x32_bf16(a[kc], b, acc[ct], 0, 0, 0);
        }
    }

    int r0 = rowbase + quad * 4;
    float di[4];
#pragma unroll
    for (int r = 0; r < 4; r++) {
        int rr = r0 + r;
        di[r] = dinv[rr < n ? rr : 0];
    }
    bool odd = lane & 1;
    uint32_t* Gu = (uint32_t*)G;
#pragma unroll
    for (int ct = 0; ct < 8; ct++) {
        float x0 = acc[ct][0], x1 = acc[ct][1], x2 = acc[ct][2], x3 = acc[ct][3];
        float y0 = __shfl_xor(x0, 1, 64), y1 = __shfl_xor(x1, 1, 64);
        float y2 = __shfl_xor(x2, 1, 64), y3 = __shfl_xor(x3, 1, 64);
        int colp = ct * 16 + (c & ~1);
        size_t sbase = (size_t)(colp >> 5) * SLABU + ((colp & 31) >> 1);
        if (!odd) {
            if (r0 + 0 < n) Gu[sbase + (size_t)(r0 + 0) * 16] = pack2bf(di[0] * x0, di[0] * y0);
            if (r0 + 1 < n) Gu[sbase + (size_t)(r0 + 1) * 16] = pack2bf(di[1] * x1, di[1] * y1);
        } else {
            if (r0 + 2 < n) Gu[sbase + (size_t)(r0 + 2) * 16] = pack2bf(di[2] * y2, di[2] * x2);
            if (r0 + 3 < n) Gu[sbase + (size_t)(r0 + 3) * 16] = pack2bf(di[3] * y3, di[3] * x3);
        }
    }
}

// ---------- layer-3 GEMM: slab-major A in, LINEAR 40-wide out ----------
__global__ __launch_bounds__(256) void gemm40_mfma(const unsigned short* __restrict__ A,
                                                   const unsigned short* __restrict__ WT,
                                                   const float* __restrict__ dinv,
                                                   unsigned short* __restrict__ G, int n) {
    int wave = threadIdx.x >> 6;
    int lane = threadIdx.x & 63;
    int quad = lane >> 4;
    int c = lane & 15;
    int rowbase = blockIdx.x * 64 + wave * 16;

    int arow = rowbase + c;
    if (arow >= n) arow = n - 1;
    const unsigned short* ap = A + (size_t)arow * 32 + quad * 8;  // slab-major
    bfx8 a[4];
#pragma unroll
    for (int kc = 0; kc < 4; kc++) a[kc] = ld8(ap + (size_t)kc * SLABE);

    f32x4 acc[3];
#pragma unroll
    for (int ct = 0; ct < 3; ct++) acc[ct] = (f32x4){0.f, 0.f, 0.f, 0.f};
#pragma unroll
    for (int ct = 0; ct < 3; ct++) {
        const unsigned short* bp = WT + (size_t)(ct * 16 + c) * 128 + quad * 8;
#pragma unroll
        for (int kc = 0; kc < 4; kc++) {
            bfx8 b = ld8(bp + kc * 32);
            acc[ct] = __builtin_amdgcn_mfma_f32_16x16x32_bf16(a[kc], b, acc[ct], 0, 0, 0);
        }
    }

    int r0 = rowbase + quad * 4;
    float di[4];
#pragma unroll
    for (int r = 0; r < 4; r++) {
        int rr = r0 + r;
        di[r] = dinv[rr < n ? rr : 0];
    }
    bool odd = lane & 1;
#pragma unroll
    for (int ct = 0; ct < 3; ct++) {
        float x0 = acc[ct][0], x1 = acc[ct][1], x2 = acc[ct][2], x3 = acc[ct][3];
        float y0 = __shfl_xor(x0, 1, 64), y1 = __shfl_xor(x1, 1, 64);
        float y2 = __shfl_xor(x2, 1, 64), y3 = __shfl_xor(x3, 1, 64);
        int colp = ct * 16 + (c & ~1);
        if (colp >= 40) continue;
        if (!odd) {
            if (r0 + 0 < n) *(uint32_t*)(&G[(size_t)(r0 + 0) * 40 + colp]) = pack2bf(di[0] * x0, di[0] * y0);
            if (r0 + 1 < n) *(uint32_t*)(&G[(size_t)(r0 + 1) * 40 + colp]) = pack2bf(di[1] * x1, di[1] * y1);
        } else {
            if (r0 + 2 < n) *(uint32_t*)(&G[(size_t)(r0 + 2) * 40 + colp]) = pack2bf(di[2] * y2, di[2] * x2);
            if (r0 + 3 < n) *(uint32_t*)(&G[(size_t)(r0 + 3) * 40 + colp]) = pack2bf(di[3] * y3, di[3] * x3);
        }
    }
}

// ---------- D4: layer-1 aggregate, slab-sliced (per-edge dinv[s]) ----------
// Block handles ONE 32-feature slab (3.2MB working set -> per-XCD L2-local
// under the %8 round-robin heuristic; even without it, 4x better locality).
// Wave = 1 node: 4 edge-slots x 16 lanes (16 uint32 = 64B slab slice),
// fully-predicated 16-edge batches (4 row-loads in flight), shfl-reduce.
__global__ __launch_bounds__(256) void agg128_l1(const unsigned short* __restrict__ G,
                                                 const int* __restrict__ row_ptr,
                                                 const int* __restrict__ deg,
                                                 const unsigned short* __restrict__ csr_src,
                                                 const float* __restrict__ dinv,
                                                 const float* __restrict__ b,
                                                 unsigned short* __restrict__ Y, int n) {
    int bi = blockIdx.x;
    int xs = bi & 7;
    int slab = xs >> 1;                      // 2 XCDs per slab under %8 heuristic
    int grp = (bi >> 3) * 2 + (xs & 1);      // node group [0,12500)
    int node = grp * 4 + (threadIdx.x >> 6);
    int l = threadIdx.x & 63;
    int j = l >> 4, f = l & 15;
    const uint32_t* Gs = (const uint32_t*)G + (size_t)slab * SLABU;

    float dn = dinv[node];
    float2 acc = make_float2(0.f, 0.f);
    if (j == 0) {
        float2 sf = bfp2f2(Gs[(size_t)node * 16 + f]);
        acc = make_float2(dn * sf.x, dn * sf.y);  // self: dinv[d]*H1[d]
    }
    int p = row_ptr[node];
    int p1 = p + deg[node];
    for (int q = p; q < p1; q += 16) {
        int i0 = q + j, i1 = q + 4 + j, i2 = q + 8 + j, i3 = q + 12 + j;
        int v0 = i0 < p1, v1 = i1 < p1, v2 = i2 < p1, v3 = i3 < p1;
        int s0 = csr_src[v0 ? i0 : p], s1 = csr_src[v1 ? i1 : p];
        int s2 = csr_src[v2 ? i2 : p], s3 = csr_src[v3 ? i3 : p];
        float d0 = v0 ? dinv[s0] : 0.f, d1 = v1 ? dinv[s1] : 0.f;
        float d2 = v2 ? dinv[s2] : 0.f, d3 = v3 ? dinv[s3] : 0.f;
        float2 f0 = bfp2f2(Gs[(size_t)s0 * 16 + f]);
        float2 f1 = bfp2f2(Gs[(size_t)s1 * 16 + f]);
        float2 f2 = bfp2f2(Gs[(size_t)s2 * 16 + f]);
        float2 f3 = bfp2f2(Gs[(size_t)s3 * 16 + f]);
        acc.x += fmaf(d0, f0.x, d1 * f1.x) + fmaf(d2, f2.x, d3 * f3.x);
        acc.y += fmaf(d0, f0.y, d1 * f1.y) + fmaf(d2, f2.y, d3 * f3.y);
    }
    acc.x += __shfl_xor(acc.x, 16, 64);
    acc.y += __shfl_xor(acc.y, 16, 64);
    acc.x += __shfl_xor(acc.x, 32, 64);
    acc.y += __shfl_xor(acc.y, 32, 64);
    float vx = fmaf(dn, acc.x, b[slab * 32 + 2 * f]);
    float vy = fmaf(dn, acc.y, b[slab * 32 + 2 * f + 1]);
    if (j == 0)
        ((uint32_t*)Y)[(size_t)slab * SLABU + (size_t)node * 16 + f] =
            pack2bf(vx > 0.f ? vx : 0.f, vy > 0.f ? vy : 0.f);
}

// ---------- D6: layer-2 aggregate, slab-sliced (G pre-scaled) ----------
__global__ __launch_bounds__(256) void agg128(const unsigned short* __restrict__ G,
                                              const int* __restrict__ row_ptr,
                                              const int* __restrict__ deg,
                                              const unsigned short* __restrict__ csr_src,
                                              const float* __restrict__ dinv,
                                              const float* __restrict__ b,
                                              unsigned short* __restrict__ Y, int n) {
    int bi = blockIdx.x;
    int xs = bi & 7;
    int slab = xs >> 1;
    int grp = (bi >> 3) * 2 + (xs & 1);
    int node = grp * 4 + (threadIdx.x >> 6);
    int l = threadIdx.x & 63;
    int j = l >> 4, f = l & 15;
    const uint32_t* Gs = (const uint32_t*)G + (size_t)slab * SLABU;

    float2 acc = make_float2(0.f, 0.f);
    if (j == 0) acc = bfp2f2(Gs[(size_t)node * 16 + f]);  // self (pre-scaled)
    int p = row_ptr[node];
    int p1 = p + deg[node];
    for (int q = p; q < p1; q += 16) {
        int i0 = q + j, i1 = q + 4 + j, i2 = q + 8 + j, i3 = q + 12 + j;
        int v0 = i0 < p1, v1 = i1 < p1, v2 = i2 < p1, v3 = i3 < p1;
        int s0 = csr_src[v0 ? i0 : p], s1 = csr_src[v1 ? i1 : p];
        int s2 = csr_src[v2 ? i2 : p], s3 = csr_src[v3 ? i3 : p];
        float w0 = v0 ? 1.f : 0.f, w1 = v1 ? 1.f : 0.f;
        float w2 = v2 ? 1.f : 0.f, w3 = v3 ? 1.f : 0.f;
        float2 f0 = bfp2f2(Gs[(size_t)s0 * 16 + f]);
        float2 f1 = bfp2f2(Gs[(size_t)s1 * 16 + f]);
        float2 f2 = bfp2f2(Gs[(size_t)s2 * 16 + f]);
        float2 f3 = bfp2f2(Gs[(size_t)s3 * 16 + f]);
        acc.x += fmaf(w0, f0.x, w1 * f1.x) + fmaf(w2, f2.x, w3 * f3.x);
        acc.y += fmaf(w0, f0.y, w1 * f1.y) + fmaf(w2, f2.y, w3 * f3.y);
    }
    acc.x += __shfl_xor(acc.x, 16, 64);
    acc.y += __shfl_xor(acc.y, 16, 64);
    acc.x += __shfl_xor(acc.x, 32, 64);
    acc.y += __shfl_xor(acc.y, 32, 64);
    float dn = dinv[node];
    float vx = fmaf(dn, acc.x, b[slab * 32 + 2 * f]);
    float vy = fmaf(dn, acc.y, b[slab * 32 + 2 * f + 1]);
    if (j == 0)
        ((uint32_t*)Y)[(size_t)slab * SLABU + (size_t)node * 16 + f] =
            pack2bf(vx > 0.f ? vx : 0.f, vy > 0.f ? vy : 0.f);
}

// ---------- D8: 40-wide aggregate + log_softmax (linear G40, ~4MB L2-scale) ----------
__global__ __launch_bounds__(256) void agg40_lsm(const unsigned short* __restrict__ G,
                                                 const int* __restrict__ row_ptr,
                                                 const int* __restrict__ deg,
                                                 const unsigned short* __restrict__ csr_src,
                                                 const float* __restrict__ dinv,
                                                 const float* __restrict__ b,
                                                 float* __restrict__ Y, int n) {
    int node = blockIdx.x * 4 + (threadIdx.x >> 6);
    if (node >= n) return;
    int lane = threadIdx.x & 63;
    bool act = lane < 40;
    int lc = act ? lane : 0;

    float acc = act ? bf2f(G[(size_t)node * 40 + lane]) : 0.f;
    int p = row_ptr[node];
    int p1 = p + deg[node];
    for (; p + 3 < p1; p += 4) {
        int s0 = csr_src[p], s1 = csr_src[p + 1], s2 = csr_src[p + 2], s3 = csr_src[p + 3];
        float f0 = bf2f(G[(size_t)s0 * 40 + lc]);
        float f1 = bf2f(G[(size_t)s1 * 40 + lc]);
        float f2 = bf2f(G[(size_t)s2 * 40 + lc]);
        float f3 = bf2f(G[(size_t)s3 * 40 + lc]);
        acc += (f0 + f1) + (f2 + f3);
    }
    for (; p < p1; ++p) acc += bf2f(G[(size_t)csr_src[p] * 40 + lc]);

    float v = act ? fmaf(dinv[node], acc, b[lane]) : -1e30f;
    float m = v;
#pragma unroll
    for (int off = 32; off > 0; off >>= 1) m = fmaxf(m, __shfl_xor(m, off, 64));
    float ex = act ? expf(v - m) : 0.f;
    float s_ = ex;
#pragma unroll
    for (int off = 32; off > 0; off >>= 1) s_ += __shfl_xor(s_, off, 64);
    float ls = logf(s_);
    if (act) Y[(size_t)node * 40 + lane] = v - m - ls;
}

// ---------- launch ----------

extern "C" void kernel_launch(void* const* d_in, const int* in_sizes, int n_in,
                              void* d_out, int out_size, void* d_ws, size_t ws_size,
                              hipStream_t stream) {
    const float* x  = (const float*)d_in[0];
    const int*   ei = (const int*)d_in[1];
    const float* W1 = (const float*)d_in[2];
    const float* b1 = (const float*)d_in[3];
    const float* W2 = (const float*)d_in[4];
    const float* b2 = (const float*)d_in[5];
    const float* W3 = (const float*)d_in[6];
    const float* b3 = (const float*)d_in[7];
    float* out = (float*)d_out;

    const int n = NN, e = NE;
    const int* srcI = ei;
    const int* dstI = ei + e;

    char* ws = (char*)d_ws;
    int*            deg     = (int*)ws;                          // n ints
    int*            row_ptr = (int*)(ws + 200704);               // n ints
    float*          dinv    = (float*)(ws + 401408);             // n fp32
    int*            cursor  = (int*)(ws + 602112);               // NB ints
    uint32_t*       packA   = (uint32_t*)(ws + 603136);          // NB*SLAB uint32 (6.4MB)
    unsigned short* csr_src = (unsigned short*)(ws + 7025664);   // E ushort (1.6MB)
    unsigned short* WT1     = (unsigned short*)(ws + 8625664);   // 128x128 bf16
    unsigned short* WT2     = (unsigned short*)(ws + 8658432);
    unsigned short* WT3     = (unsigned short*)(ws + 8691200);   // 48x128 bf16
    unsigned short* bufG    = (unsigned short*)(ws + 8703488);   // 4 slabs x NRP x 32 bf16 (12.8MB)
    unsigned short* bufA    = (unsigned short*)(ws + 21515776);  // 4 slabs x NRP x 32 bf16 (12.8MB)

    // D1: W transposes + zero cursors
    prep<<<153, 256, 0, stream>>>(W1, W2, W3, WT1, WT2, WT3, cursor);
    // D2: layer-1 GEMM (slab-major out) ∪ slab scatter
    gemm1_hist<<<GG + SB, 256, 0, stream>>>(x, WT1, bufG, n, srcI, dstI, cursor, packA, e);
    // D3: per-bucket sort -> CSR + row_ptr/deg/dinv
    buildB<<<NB, 256, 0, stream>>>(packA, cursor, row_ptr, deg, dinv, csr_src, n);
    // D4: aggregate layer 1 (slab-sliced, per-edge dinv)
    agg128_l1<<<50000, 256, 0, stream>>>(bufG, row_ptr, deg, csr_src, dinv, b1, bufA, n);
    // D5: layer-2 GEMM (slab in/out, pre-scaled)
    gemm128_mfma<<<GG, 256, 0, stream>>>(bufA, WT2, dinv, bufG, n);
    // D6: aggregate layer 2 (slab-sliced)
    agg128<<<50000, 256, 0, stream>>>(bufG, row_ptr, deg, csr_src, dinv, b2, bufA, n);
    // D7: layer-3 GEMM (slab in, linear 40-wide out)
    gemm40_mfma<<<GG, 256, 0, stream>>>(bufA, WT3, dinv, bufG, n);
    // D8: aggregate + log_softmax -> out
    agg40_lsm<<<(n + 3) / 4, 256, 0, stream>>>(bufG, row_ptr, deg, csr_src, dinv, b3, out, n);
}

// Round 5
// 271.776 us; speedup vs baseline: 1.2974x; 1.2974x over previous
//
#include <hip/hip_runtime.h>
#include <stdint.h>

#define NN 50000
#define NE 800000
#define GG 782     // gemm grid: (NN + 63) / 64
#define NB 196     // hi buckets: ceil(NN / 256)
#define TT 2048    // edges per scatter block
#define SB 391     // scatter blocks: ceil(NE / TT)
#define SLAB 8192  // packA slab stride per bucket

typedef __attribute__((ext_vector_type(8))) short bfx8;   // 8 bf16 (4 VGPRs)
typedef __attribute__((ext_vector_type(4))) float f32x4;  // MFMA acc

// ---- bf16 helpers (RNE) ----
__device__ inline unsigned short f2bf(float f) {
    union { float f; uint32_t u; } x; x.f = f;
    uint32_t u = x.u;
    return (unsigned short)((u + 0x7fffu + ((u >> 16) & 1u)) >> 16);
}
__device__ inline uint32_t pack2bf(float lo, float hi) {
    return (uint32_t)f2bf(lo) | ((uint32_t)f2bf(hi) << 16);
}
__device__ inline float bf2f(unsigned short h) {
    union { uint32_t u; float f; } c; c.u = ((uint32_t)h) << 16;
    return c.f;
}
__device__ inline float2 bfp2f2(uint32_t v) {
    union { uint32_t u; float f; } a, b;
    a.u = (v & 0xffffu) << 16;
    b.u = v & 0xffff0000u;
    return make_float2(a.f, b.f);
}
__device__ inline bfx8 ld8(const unsigned short* p) {
    union { uint4 u; bfx8 v; } c;
    c.u = *(const uint4*)p;
    return c.v;
}
__device__ inline bfx8 cvt8(float4 u, float4 v) {
    union { unsigned short s[8]; bfx8 r; } c;
    c.s[0] = f2bf(u.x); c.s[1] = f2bf(u.y); c.s[2] = f2bf(u.z); c.s[3] = f2bf(u.w);
    c.s[4] = f2bf(v.x); c.s[5] = f2bf(v.y); c.s[6] = f2bf(v.z); c.s[7] = f2bf(v.w);
    return c.r;
}

// ---------- D1: W transposes + zero bucket cursors ----------
__global__ void prep(const float* __restrict__ W1, const float* __restrict__ W2,
                     const float* __restrict__ W3,
                     unsigned short* __restrict__ WT1, unsigned short* __restrict__ WT2,
                     unsigned short* __restrict__ WT3, int* __restrict__ cursor) {
    if (blockIdx.x == 152) {
        if (threadIdx.x < NB) cursor[threadIdx.x] = 0;
        return;
    }
    int w = blockIdx.x * 256 + threadIdx.x;
    if (w < 16384) {
        int nn = w >> 7, k = w & 127;
        WT1[nn * 128 + k] = f2bf(W1[k * 128 + nn]);
    } else if (w < 32768) {
        int w2 = w - 16384, nn = w2 >> 7, k = w2 & 127;
        WT2[nn * 128 + k] = f2bf(W2[k * 128 + nn]);
    } else if (w < 38912) {
        int w2 = w - 32768, nn = w2 >> 7, k = w2 & 127;  // 48x128, zero-pad
        WT3[nn * 128 + k] = (nn < 40) ? f2bf(W3[k * 40 + nn]) : (unsigned short)0;
    }
}

// ---------- D2: layer-1 GEMM ∪ bucket-scatter (cursor-reservation) ----------
__global__ __launch_bounds__(256) void gemm1_hist(const float* __restrict__ X,
                                                  const unsigned short* __restrict__ WT,
                                                  unsigned short* __restrict__ G, int n,
                                                  const int* __restrict__ src,
                                                  const int* __restrict__ dst,
                                                  int* __restrict__ cursor,
                                                  uint32_t* __restrict__ packA, int e) {
    __shared__ int lc[NB];
    __shared__ int gb[NB];
    if (blockIdx.x >= GG) {
        int b = blockIdx.x - GG;
        int t = threadIdx.x;
        if (t < NB) lc[t] = 0;
        __syncthreads();
        int start = b * TT;
        int end = start + TT; if (end > e) end = e;
        int hi_[8], r_[8];
        uint32_t pk_[8];
#pragma unroll
        for (int j = 0; j < 8; j++) {
            int i = start + j * 256 + t;
            if (i < end) {
                int dd = dst[i], ss = src[i];
                hi_[j] = dd >> 8;
                pk_[j] = ((uint32_t)dd << 16) | (uint32_t)ss;
                r_[j] = atomicAdd(&lc[hi_[j]], 1);  // LDS rank
            } else r_[j] = -1;
        }
        __syncthreads();
        if (t < NB) {
            int c = lc[t];
            gb[t] = c ? atomicAdd(&cursor[t], c) : 0;  // global slab reservation
        }
        __syncthreads();
#pragma unroll
        for (int j = 0; j < 8; j++) {
            if (r_[j] >= 0)
                packA[(size_t)hi_[j] * SLAB + gb[hi_[j]] + r_[j]] = pk_[j];
        }
        return;
    }
    int wave = threadIdx.x >> 6;
    int lane = threadIdx.x & 63;
    int quad = lane >> 4;
    int c = lane & 15;
    int rowbase = blockIdx.x * 64 + wave * 16;

    int arow = rowbase + c;
    if (arow >= n) arow = n - 1;
    const float* ap = X + (size_t)arow * 128 + quad * 8;
    bfx8 a[4];
#pragma unroll
    for (int kc = 0; kc < 4; kc++) {
        float4 u = *(const float4*)(ap + kc * 32);
        float4 v = *(const float4*)(ap + kc * 32 + 4);
        a[kc] = cvt8(u, v);
    }

    f32x4 acc[8];
#pragma unroll
    for (int ct = 0; ct < 8; ct++) acc[ct] = (f32x4){0.f, 0.f, 0.f, 0.f};
#pragma unroll
    for (int ct = 0; ct < 8; ct++) {
        const unsigned short* bp = WT + (size_t)(ct * 16 + c) * 128 + quad * 8;
#pragma unroll
        for (int kc = 0; kc < 4; kc++) {
            bfx8 b = ld8(bp + kc * 32);
            acc[ct] = __builtin_amdgcn_mfma_f32_16x16x32_bf16(a[kc], b, acc[ct], 0, 0, 0);
        }
    }

    int r0 = rowbase + quad * 4;
    bool odd = lane & 1;
#pragma unroll
    for (int ct = 0; ct < 8; ct++) {
        float x0 = acc[ct][0], x1 = acc[ct][1], x2 = acc[ct][2], x3 = acc[ct][3];
        float y0 = __shfl_xor(x0, 1, 64), y1 = __shfl_xor(x1, 1, 64);
        float y2 = __shfl_xor(x2, 1, 64), y3 = __shfl_xor(x3, 1, 64);
        int colp = ct * 16 + (c & ~1);
        if (!odd) {
            if (r0 + 0 < n) *(uint32_t*)(&G[(size_t)(r0 + 0) * 128 + colp]) = pack2bf(x0, y0);
            if (r0 + 1 < n) *(uint32_t*)(&G[(size_t)(r0 + 1) * 128 + colp]) = pack2bf(x1, y1);
        } else {
            if (r0 + 2 < n) *(uint32_t*)(&G[(size_t)(r0 + 2) * 128 + colp]) = pack2bf(y2, x2);
            if (r0 + 3 < n) *(uint32_t*)(&G[(size_t)(r0 + 3) * 128 + colp]) = pack2bf(y3, x3);
        }
    }
}

// ---------- D3: per-bucket fine sort -> row_ptr/deg/dinv + csr_src ----------
__global__ __launch_bounds__(256) void buildB(const uint32_t* __restrict__ packA,
                                              const int* __restrict__ cursor,
                                              int* __restrict__ row_ptr, int* __restrict__ deg,
                                              float* __restrict__ dinv,
                                              unsigned short* __restrict__ csr_src, int n) {
    __shared__ int s[256];
    __shared__ int cnt[256];
    __shared__ int rp[256];
    __shared__ int basehi, bcnt;
    int hi = blockIdx.x;
    int t = threadIdx.x;
    int bc = (t < NB) ? cursor[t] : 0;
    s[t] = bc;
    __syncthreads();
#pragma unroll
    for (int off = 1; off < 256; off <<= 1) {
        int y = (t >= off) ? s[t - off] : 0;
        __syncthreads();
        s[t] += y;
        __syncthreads();
    }
    if (t == hi) { basehi = s[t] - bc; bcnt = bc; }
    cnt[t] = 0;
    __syncthreads();
    int b0 = basehi;
    int mc = bcnt;
    const uint32_t* slab = packA + (size_t)hi * SLAB;
    for (int i = t; i < mc; i += 256)
        atomicAdd(&cnt[(slab[i] >> 16) & 0xFF], 1);  // LDS
    __syncthreads();
    int v = cnt[t];
    s[t] = v;
    __syncthreads();
#pragma unroll
    for (int off = 1; off < 256; off <<= 1) {
        int y = (t >= off) ? s[t - off] : 0;
        __syncthreads();
        s[t] += y;
        __syncthreads();
    }
    rp[t] = b0 + s[t] - v;  // absolute row start for node hi*256+t
    int node = hi * 256 + t;
    if (node < n) {
        row_ptr[node] = rp[t];
        deg[node] = v;
        dinv[node] = rsqrtf(1.0f + (float)v);
    }
    cnt[t] = 0;
    __syncthreads();
    for (int i = t; i < mc; i += 256) {
        uint32_t p = slab[i];
        int lo = (p >> 16) & 0xFF;
        int r = atomicAdd(&cnt[lo], 1);  // LDS
        csr_src[rp[lo] + r] = (unsigned short)(p & 0xFFFF);
    }
}

// ---------- GEMMs for layers 2/3: pre-scale rows by dinv (epilogue) ----------
__global__ __launch_bounds__(256) void gemm128_mfma(const unsigned short* __restrict__ A,
                                                    const unsigned short* __restrict__ WT,
                                                    const float* __restrict__ dinv,
                                                    unsigned short* __restrict__ G, int n) {
    int wave = threadIdx.x >> 6;
    int lane = threadIdx.x & 63;
    int quad = lane >> 4;
    int c = lane & 15;
    int rowbase = blockIdx.x * 64 + wave * 16;

    int arow = rowbase + c;
    if (arow >= n) arow = n - 1;
    const unsigned short* ap = A + (size_t)arow * 128 + quad * 8;
    bfx8 a[4];
#pragma unroll
    for (int kc = 0; kc < 4; kc++) a[kc] = ld8(ap + kc * 32);

    f32x4 acc[8];
#pragma unroll
    for (int ct = 0; ct < 8; ct++) acc[ct] = (f32x4){0.f, 0.f, 0.f, 0.f};
#pragma unroll
    for (int ct = 0; ct < 8; ct++) {
        const unsigned short* bp = WT + (size_t)(ct * 16 + c) * 128 + quad * 8;
#pragma unroll
        for (int kc = 0; kc < 4; kc++) {
            bfx8 b = ld8(bp + kc * 32);
            acc[ct] = __builtin_amdgcn_mfma_f32_16x16x32_bf16(a[kc], b, acc[ct], 0, 0, 0);
        }
    }

    int r0 = rowbase + quad * 4;
    float di[4];
#pragma unroll
    for (int r = 0; r < 4; r++) {
        int rr = r0 + r;
        di[r] = dinv[rr < n ? rr : 0];
    }
    bool odd = lane & 1;
#pragma unroll
    for (int ct = 0; ct < 8; ct++) {
        float x0 = acc[ct][0], x1 = acc[ct][1], x2 = acc[ct][2], x3 = acc[ct][3];
        float y0 = __shfl_xor(x0, 1, 64), y1 = __shfl_xor(x1, 1, 64);
        float y2 = __shfl_xor(x2, 1, 64), y3 = __shfl_xor(x3, 1, 64);
        int colp = ct * 16 + (c & ~1);
        if (!odd) {
            if (r0 + 0 < n) *(uint32_t*)(&G[(size_t)(r0 + 0) * 128 + colp]) = pack2bf(di[0] * x0, di[0] * y0);
            if (r0 + 1 < n) *(uint32_t*)(&G[(size_t)(r0 + 1) * 128 + colp]) = pack2bf(di[1] * x1, di[1] * y1);
        } else {
            if (r0 + 2 < n) *(uint32_t*)(&G[(size_t)(r0 + 2) * 128 + colp]) = pack2bf(di[2] * y2, di[2] * x2);
            if (r0 + 3 < n) *(uint32_t*)(&G[(size_t)(r0 + 3) * 128 + colp]) = pack2bf(di[3] * y3, di[3] * x3);
        }
    }
}

__global__ __launch_bounds__(256) void gemm40_mfma(const unsigned short* __restrict__ A,
                                                   const unsigned short* __restrict__ WT,
                                                   const float* __restrict__ dinv,
                                                   unsigned short* __restrict__ G, int n) {
    int wave = threadIdx.x >> 6;
    int lane = threadIdx.x & 63;
    int quad = lane >> 4;
    int c = lane & 15;
    int rowbase = blockIdx.x * 64 + wave * 16;

    int arow = rowbase + c;
    if (arow >= n) arow = n - 1;
    const unsigned short* ap = A + (size_t)arow * 128 + quad * 8;
    bfx8 a[4];
#pragma unroll
    for (int kc = 0; kc < 4; kc++) a[kc] = ld8(ap + kc * 32);

    f32x4 acc[3];
#pragma unroll
    for (int ct = 0; ct < 3; ct++) acc[ct] = (f32x4){0.f, 0.f, 0.f, 0.f};
#pragma unroll
    for (int ct = 0; ct < 3; ct++) {
        const unsigned short* bp = WT + (size_t)(ct * 16 + c) * 128 + quad * 8;
#pragma unroll
        for (int kc = 0; kc < 4; kc++) {
            bfx8 b = ld8(bp + kc * 32);
            acc[ct] = __builtin_amdgcn_mfma_f32_16x16x32_bf16(a[kc], b, acc[ct], 0, 0, 0);
        }
    }

    int r0 = rowbase + quad * 4;
    float di[4];
#pragma unroll
    for (int r = 0; r < 4; r++) {
        int rr = r0 + r;
        di[r] = dinv[rr < n ? rr : 0];
    }
    bool odd = lane & 1;
#pragma unroll
    for (int ct = 0; ct < 3; ct++) {
        float x0 = acc[ct][0], x1 = acc[ct][1], x2 = acc[ct][2], x3 = acc[ct][3];
        float y0 = __shfl_xor(x0, 1, 64), y1 = __shfl_xor(x1, 1, 64);
        float y2 = __shfl_xor(x2, 1, 64), y3 = __shfl_xor(x3, 1, 64);
        int colp = ct * 16 + (c & ~1);
        if (colp >= 40) continue;
        if (!odd) {
            if (r0 + 0 < n) *(uint32_t*)(&G[(size_t)(r0 + 0) * 40 + colp]) = pack2bf(di[0] * x0, di[0] * y0);
            if (r0 + 1 < n) *(uint32_t*)(&G[(size_t)(r0 + 1) * 40 + colp]) = pack2bf(di[1] * x1, di[1] * y1);
        } else {
            if (r0 + 2 < n) *(uint32_t*)(&G[(size_t)(r0 + 2) * 40 + colp]) = pack2bf(di[2] * y2, di[2] * x2);
            if (r0 + 3 < n) *(uint32_t*)(&G[(size_t)(r0 + 3) * 40 + colp]) = pack2bf(di[3] * y3, di[3] * x3);
        }
    }
}

// ---------- D4: layer-1 aggregate, uint2 gather (2 edges per load instr) ----------
// wave = node; h = lane>>5 is the edge slot, fl = lane&31 the uint2 within the
// 256B row. One 64-lane dwordx2 load fetches TWO edges' rows (512B). 4 loads
// in flight per 8-edge batch. Per-edge dinv[s] weights (H1 is unscaled).
__global__ __launch_bounds__(256) void agg128_l1(const unsigned short* __restrict__ G,
                                                 const int* __restrict__ row_ptr,
                                                 const int* __restrict__ deg,
                                                 const unsigned short* __restrict__ csr_src,
                                                 const float* __restrict__ dinv,
                                                 const float* __restrict__ b,
                                                 unsigned short* __restrict__ Y, int n) {
    int node = blockIdx.x * 4 + (threadIdx.x >> 6);
    if (node >= n) return;
    int l = threadIdx.x & 63;
    int h = l >> 5, fl = l & 31;
    const uint2* Gr = (const uint2*)G;  // row = 32 uint2 (256B)

    float dn = dinv[node];
    float4 acc = make_float4(0.f, 0.f, 0.f, 0.f);
    if (h == 0) {
        uint2 sq = Gr[(size_t)node * 32 + fl];
        float2 a0 = bfp2f2(sq.x), a1 = bfp2f2(sq.y);
        acc = make_float4(dn * a0.x, dn * a0.y, dn * a1.x, dn * a1.y);  // self
    }
    int p = row_ptr[node];
    int p1 = p + deg[node];
    for (int q = p; q < p1; q += 8) {
        int i0 = q + h, i1 = q + 2 + h, i2 = q + 4 + h, i3 = q + 6 + h;
        bool v0 = i0 < p1, v1 = i1 < p1, v2 = i2 < p1, v3 = i3 < p1;
        int s0 = csr_src[v0 ? i0 : p], s1 = csr_src[v1 ? i1 : p];
        int s2 = csr_src[v2 ? i2 : p], s3 = csr_src[v3 ? i3 : p];
        float d0 = v0 ? dinv[s0] : 0.f, d1 = v1 ? dinv[s1] : 0.f;
        float d2 = v2 ? dinv[s2] : 0.f, d3 = v3 ? dinv[s3] : 0.f;
        uint2 q0 = Gr[(size_t)s0 * 32 + fl], q1 = Gr[(size_t)s1 * 32 + fl];
        uint2 q2 = Gr[(size_t)s2 * 32 + fl], q3 = Gr[(size_t)s3 * 32 + fl];
        float2 x0 = bfp2f2(q0.x), y0 = bfp2f2(q0.y);
        float2 x1 = bfp2f2(q1.x), y1 = bfp2f2(q1.y);
        float2 x2 = bfp2f2(q2.x), y2 = bfp2f2(q2.y);
        float2 x3 = bfp2f2(q3.x), y3 = bfp2f2(q3.y);
        acc.x += fmaf(d0, x0.x, d1 * x1.x) + fmaf(d2, x2.x, d3 * x3.x);
        acc.y += fmaf(d0, x0.y, d1 * x1.y) + fmaf(d2, x2.y, d3 * x3.y);
        acc.z += fmaf(d0, y0.x, d1 * y1.x) + fmaf(d2, y2.x, d3 * y3.x);
        acc.w += fmaf(d0, y0.y, d1 * y1.y) + fmaf(d2, y2.y, d3 * y3.y);
    }
    acc.x += __shfl_xor(acc.x, 32, 64);
    acc.y += __shfl_xor(acc.y, 32, 64);
    acc.z += __shfl_xor(acc.z, 32, 64);
    acc.w += __shfl_xor(acc.w, 32, 64);
    float4 bb = ((const float4*)b)[fl];
    float r0 = fmaf(dn, acc.x, bb.x);
    float r1 = fmaf(dn, acc.y, bb.y);
    float r2 = fmaf(dn, acc.z, bb.z);
    float r3 = fmaf(dn, acc.w, bb.w);
    if (h == 0) {
        uint2 o;
        o.x = pack2bf(r0 > 0.f ? r0 : 0.f, r1 > 0.f ? r1 : 0.f);
        o.y = pack2bf(r2 > 0.f ? r2 : 0.f, r3 > 0.f ? r3 : 0.f);
        ((uint2*)Y)[(size_t)node * 32 + fl] = o;
    }
}

// ---------- D6: layer-2 aggregate, uint2 gather (G pre-scaled) ----------
__global__ __launch_bounds__(256) void agg128(const unsigned short* __restrict__ G,
                                              const int* __restrict__ row_ptr,
                                              const int* __restrict__ deg,
                                              const unsigned short* __restrict__ csr_src,
                                              const float* __restrict__ dinv,
                                              const float* __restrict__ b,
                                              unsigned short* __restrict__ Y, int n) {
    int node = blockIdx.x * 4 + (threadIdx.x >> 6);
    if (node >= n) return;
    int l = threadIdx.x & 63;
    int h = l >> 5, fl = l & 31;
    const uint2* Gr = (const uint2*)G;

    float4 acc = make_float4(0.f, 0.f, 0.f, 0.f);
    if (h == 0) {
        uint2 sq = Gr[(size_t)node * 32 + fl];
        float2 a0 = bfp2f2(sq.x), a1 = bfp2f2(sq.y);
        acc = make_float4(a0.x, a0.y, a1.x, a1.y);  // self (pre-scaled)
    }
    int p = row_ptr[node];
    int p1 = p + deg[node];
    for (int q = p; q < p1; q += 8) {
        int i0 = q + h, i1 = q + 2 + h, i2 = q + 4 + h, i3 = q + 6 + h;
        bool v0 = i0 < p1, v1 = i1 < p1, v2 = i2 < p1, v3 = i3 < p1;
        int s0 = csr_src[v0 ? i0 : p], s1 = csr_src[v1 ? i1 : p];
        int s2 = csr_src[v2 ? i2 : p], s3 = csr_src[v3 ? i3 : p];
        float d0 = v0 ? 1.f : 0.f, d1 = v1 ? 1.f : 0.f;
        float d2 = v2 ? 1.f : 0.f, d3 = v3 ? 1.f : 0.f;
        uint2 q0 = Gr[(size_t)s0 * 32 + fl], q1 = Gr[(size_t)s1 * 32 + fl];
        uint2 q2 = Gr[(size_t)s2 * 32 + fl], q3 = Gr[(size_t)s3 * 32 + fl];
        float2 x0 = bfp2f2(q0.x), y0 = bfp2f2(q0.y);
        float2 x1 = bfp2f2(q1.x), y1 = bfp2f2(q1.y);
        float2 x2 = bfp2f2(q2.x), y2 = bfp2f2(q2.y);
        float2 x3 = bfp2f2(q3.x), y3 = bfp2f2(q3.y);
        acc.x += fmaf(d0, x0.x, d1 * x1.x) + fmaf(d2, x2.x, d3 * x3.x);
        acc.y += fmaf(d0, x0.y, d1 * x1.y) + fmaf(d2, x2.y, d3 * x3.y);
        acc.z += fmaf(d0, y0.x, d1 * y1.x) + fmaf(d2, y2.x, d3 * y3.x);
        acc.w += fmaf(d0, y0.y, d1 * y1.y) + fmaf(d2, y2.y, d3 * y3.y);
    }
    acc.x += __shfl_xor(acc.x, 32, 64);
    acc.y += __shfl_xor(acc.y, 32, 64);
    acc.z += __shfl_xor(acc.z, 32, 64);
    acc.w += __shfl_xor(acc.w, 32, 64);
    float dn = dinv[node];
    float4 bb = ((const float4*)b)[fl];
    float r0 = fmaf(dn, acc.x, bb.x);
    float r1 = fmaf(dn, acc.y, bb.y);
    float r2 = fmaf(dn, acc.z, bb.z);
    float r3 = fmaf(dn, acc.w, bb.w);
    if (h == 0) {
        uint2 o;
        o.x = pack2bf(r0 > 0.f ? r0 : 0.f, r1 > 0.f ? r1 : 0.f);
        o.y = pack2bf(r2 > 0.f ? r2 : 0.f, r3 > 0.f ? r3 : 0.f);
        ((uint2*)Y)[(size_t)node * 32 + fl] = o;
    }
}

// ---------- D8: 40-wide aggregate + log_softmax, uint2 gather ----------
// Row = 40 bf16 = 10 uint2. Lanes fl<10 active; 2 edges per instruction.
// Softmax over 40 classes held as 4-per-lane across 10 lanes (16-lane group
// shuffles; inactive lanes contribute -inf/0).
__global__ __launch_bounds__(256) void agg40_lsm(const unsigned short* __restrict__ G,
                                                 const int* __restrict__ row_ptr,
                                                 const int* __restrict__ deg,
                                                 const unsigned short* __restrict__ csr_src,
                                                 const float* __restrict__ dinv,
                                                 const float* __restrict__ b,
                                                 float* __restrict__ Y, int n) {
    int node = blockIdx.x * 4 + (threadIdx.x >> 6);
    if (node >= n) return;
    int l = threadIdx.x & 63;
    int h = l >> 5, fl = l & 31;
    bool act = fl < 10;
    int flc = act ? fl : 0;
    const uint2* Gr = (const uint2*)G;  // row = 10 uint2 (80B)

    float4 acc = make_float4(0.f, 0.f, 0.f, 0.f);
    if (h == 0) {
        uint2 sq = Gr[(size_t)node * 10 + flc];
        float2 a0 = bfp2f2(sq.x), a1 = bfp2f2(sq.y);
        acc = make_float4(a0.x, a0.y, a1.x, a1.y);  // self (pre-scaled)
    }
    int p = row_ptr[node];
    int p1 = p + deg[node];
    for (int q = p; q < p1; q += 8) {
        int i0 = q + h, i1 = q + 2 + h, i2 = q + 4 + h, i3 = q + 6 + h;
        bool v0 = i0 < p1, v1 = i1 < p1, v2 = i2 < p1, v3 = i3 < p1;
        int s0 = csr_src[v0 ? i0 : p], s1 = csr_src[v1 ? i1 : p];
        int s2 = csr_src[v2 ? i2 : p], s3 = csr_src[v3 ? i3 : p];
        float d0 = v0 ? 1.f : 0.f, d1 = v1 ? 1.f : 0.f;
        float d2 = v2 ? 1.f : 0.f, d3 = v3 ? 1.f : 0.f;
        uint2 q0 = Gr[(size_t)s0 * 10 + flc], q1 = Gr[(size_t)s1 * 10 + flc];
        uint2 q2 = Gr[(size_t)s2 * 10 + flc], q3 = Gr[(size_t)s3 * 10 + flc];
        float2 x0 = bfp2f2(q0.x), y0 = bfp2f2(q0.y);
        float2 x1 = bfp2f2(q1.x), y1 = bfp2f2(q1.y);
        float2 x2 = bfp2f2(q2.x), y2 = bfp2f2(q2.y);
        float2 x3 = bfp2f2(q3.x), y3 = bfp2f2(q3.y);
        acc.x += fmaf(d0, x0.x, d1 * x1.x) + fmaf(d2, x2.x, d3 * x3.x);
        acc.y += fmaf(d0, x0.y, d1 * x1.y) + fmaf(d2, x2.y, d3 * x3.y);
        acc.z += fmaf(d0, y0.x, d1 * y1.x) + fmaf(d2, y2.x, d3 * y3.x);
        acc.w += fmaf(d0, y0.y, d1 * y1.y) + fmaf(d2, y2.y, d3 * y3.y);
    }
    acc.x += __shfl_xor(acc.x, 32, 64);
    acc.y += __shfl_xor(acc.y, 32, 64);
    acc.z += __shfl_xor(acc.z, 32, 64);
    acc.w += __shfl_xor(acc.w, 32, 64);
    float dn = dinv[node];
    const float4* b4 = (const float4*)b;  // 40 floats = 10 float4
    float4 bb = b4[flc];
    float v0_ = fmaf(dn, acc.x, bb.x);
    float v1_ = fmaf(dn, acc.y, bb.y);
    float v2_ = fmaf(dn, acc.z, bb.z);
    float v3_ = fmaf(dn, acc.w, bb.w);
    float m = act ? fmaxf(fmaxf(v0_, v1_), fmaxf(v2_, v3_)) : -1e30f;
#pragma unroll
    for (int off = 8; off > 0; off >>= 1) m = fmaxf(m, __shfl_xor(m, off, 16));
    float e0 = act ? expf(v0_ - m) : 0.f;
    float e1 = act ? expf(v1_ - m) : 0.f;
    float e2 = act ? expf(v2_ - m) : 0.f;
    float e3 = act ? expf(v3_ - m) : 0.f;
    float s_ = ((e0 + e1) + (e2 + e3));
#pragma unroll
    for (int off = 8; off > 0; off >>= 1) s_ += __shfl_xor(s_, off, 16);
    float ls = logf(s_) + m;
    if (h == 0 && act) {
        float4 o = make_float4(v0_ - ls, v1_ - ls, v2_ - ls, v3_ - ls);
        ((float4*)Y)[(size_t)node * 10 + fl] = o;
    }
}

// ---------- launch ----------

extern "C" void kernel_launch(void* const* d_in, const int* in_sizes, int n_in,
                              void* d_out, int out_size, void* d_ws, size_t ws_size,
                              hipStream_t stream) {
    const float* x  = (const float*)d_in[0];
    const int*   ei = (const int*)d_in[1];
    const float* W1 = (const float*)d_in[2];
    const float* b1 = (const float*)d_in[3];
    const float* W2 = (const float*)d_in[4];
    const float* b2 = (const float*)d_in[5];
    const float* W3 = (const float*)d_in[6];
    const float* b3 = (const float*)d_in[7];
    float* out = (float*)d_out;

    const int n = NN, e = NE;
    const int* srcI = ei;
    const int* dstI = ei + e;

    char* ws = (char*)d_ws;
    int*            deg     = (int*)ws;                          // n ints
    int*            row_ptr = (int*)(ws + 200704);               // n ints
    float*          dinv    = (float*)(ws + 401408);             // n fp32
    int*            cursor  = (int*)(ws + 602112);               // NB ints
    uint32_t*       packA   = (uint32_t*)(ws + 603136);          // NB*SLAB uint32 (6.4MB)
    unsigned short* csr_src = (unsigned short*)(ws + 7025664);   // E ushort (1.6MB)
    unsigned short* WT1     = (unsigned short*)(ws + 8625664);   // 128x128 bf16
    unsigned short* WT2     = (unsigned short*)(ws + 8658432);
    unsigned short* WT3     = (unsigned short*)(ws + 8691200);   // 48x128 bf16
    unsigned short* bufG    = (unsigned short*)(ws + 8703488);   // n*128 bf16
    unsigned short* bufA    = (unsigned short*)(ws + 21503488);  // n*128 bf16

    // D1: W transposes + zero cursors
    prep<<<153, 256, 0, stream>>>(W1, W2, W3, WT1, WT2, WT3, cursor);
    // D2: layer-1 GEMM (unscaled) ∪ slab scatter
    gemm1_hist<<<GG + SB, 256, 0, stream>>>(x, WT1, bufG, n, srcI, dstI, cursor, packA, e);
    // D3: per-bucket sort -> CSR + row_ptr/deg/dinv
    buildB<<<NB, 256, 0, stream>>>(packA, cursor, row_ptr, deg, dinv, csr_src, n);
    // D4: aggregate layer 1 (uint2 gather, per-edge dinv)
    agg128_l1<<<(n + 3) / 4, 256, 0, stream>>>(bufG, row_ptr, deg, csr_src, dinv, b1, bufA, n);
    // D5: layer-2 GEMM (pre-scaled)
    gemm128_mfma<<<GG, 256, 0, stream>>>(bufA, WT2, dinv, bufG, n);
    // D6: aggregate layer 2 (uint2 gather)
    agg128<<<(n + 3) / 4, 256, 0, stream>>>(bufG, row_ptr, deg, csr_src, dinv, b2, bufA, n);
    // D7: layer-3 GEMM (40-wide, pre-scaled)
    gemm40_mfma<<<GG, 256, 0, stream>>>(bufA, WT3, dinv, bufG, n);
    // D8: aggregate + log_softmax -> out
    agg40_lsm<<<(n + 3) / 4, 256, 0, stream>>>(bufG, row_ptr, deg, csr_src, dinv, b3, out, n);
}